// Round 21
// baseline (57.941 us; speedup 1.0000x reference)
//
#include <hip/hip_runtime.h>

#define BLOCK 512
#define ROWS_PER_BLOCK 512
#define PHASE 256

typedef unsigned int uint_t;

__device__ __forceinline__ unsigned short f2bf(float f) {   // RNE f32->bf16
    uint_t u = __builtin_bit_cast(uint_t, f);
    u = u + 0x7FFFu + ((u >> 16) & 1u);
    return (unsigned short)(u >> 16);
}
__device__ __forceinline__ float bflo(uint_t u) { uint_t v = u << 16;         return __builtin_bit_cast(float, v); }
__device__ __forceinline__ float bfhi(uint_t u) { uint_t v = u & 0xFFFF0000u; return __builtin_bit_cast(float, v); }

__device__ __forceinline__ void idx_of(float x, float lo, float inv_range_times_nm1,
                                       int n, int& i0, float& f) {
    float t = (x - lo) * inv_range_times_nm1;
    t = fminf(fmaxf(t, 0.0f), (float)(n - 1));
    int i = (int)t;                 // t >= 0, truncation == floor
    if (i > n - 2) i = n - 2;
    i0 = i;
    f = t - (float)i;
}

__global__ __launch_bounds__(BLOCK, 4)
void nlplant_kernel(const float* __restrict__ xu,
                    const float* __restrict__ tab3,
                    const float* __restrict__ tab2,
                    const float* __restrict__ tab1,
                    const float* __restrict__ tab_eta,
                    float* __restrict__ out, int nrows)
{
    // CHAMPION (R18/R20, 55.5-55.8us bench) + s_setprio(1) around the
    // gather+physics region. Mechanism (T5/m191): 2 independent blocks/CU at
    // different phases -> priority favors the computing block's waves over the
    // neighbor's staging loads. (Null on lockstep structures; this one is the
    // favorable case.) Everything else byte-for-byte the champion.
    //  s_t3a : tab3 ch0-3 bf16-packed                                  15200 B
    //  s_t3b : tab3 ch4 f32 flat (bank = idx%32, uniform)               7600 B
    //  s_tab2: bf16-packed, 8 dwords/corner, stride 12                 18240 B
    //  s_tab1: f32 stride-28 rows; eta tail @560                        2272 B
    //  s_io  : 256 rows x 17 in/out staging                            17408 B
    // Total 60720 B -> 2 blocks/CU.
    __shared__ uint_t s_t3a[1900 * 2];
    __shared__ float  s_t3b[1900];
    __shared__ __align__(16) uint_t s_tab2[380 * 12];
    __shared__ __align__(16) float  s_tab1[568];
    __shared__ __align__(16) float  s_io[PHASE * 17];

    const int tid = threadIdx.x;

    // ---------------- stage tables: coalesced reads, zero div/mod -------------
    for (int idx = tid; idx < 1900; idx += BLOCK) {    // tab3 src [c][a][b][e]
        const float c0 = tab3[idx],        c1 = tab3[1900 + idx];
        const float c2 = tab3[3800 + idx], c3 = tab3[5700 + idx];
        s_t3a[2 * idx]     = (uint_t)f2bf(c0) | ((uint_t)f2bf(c1) << 16);
        s_t3a[2 * idx + 1] = (uint_t)f2bf(c2) | ((uint_t)f2bf(c3) << 16);
        s_t3b[idx] = tab3[7600 + idx];
    }
    if (tid < 380) {                                   // tab2 src [c][a][b]
#pragma unroll
        for (int d = 0; d < 8; ++d) {
            const float e0 = tab2[(2 * d) * 380 + tid];
            const float e1 = tab2[(2 * d + 1) * 380 + tid];
            s_tab2[tid * 12 + d] = (uint_t)f2bf(e0) | ((uint_t)f2bf(e1) << 16);
        }
    }
    if (tid < 420) {                                   // tab1 src [c][a]
        const int ch = tid / 20;                       // const-divide -> magic mul
        const int ia = tid - ch * 20;
        s_tab1[ia * 28 + ch] = tab1[tid];
    }
    if (tid < 5) s_tab1[560 + tid] = tab_eta[tid];
    // (first phase barrier below covers table staging)

    // ---------------- input: 2 phases x 256 rows ------------------------------
    const int base = blockIdx.x * ROWS_PER_BLOCK;
    const int own = tid >> 8;           // phase that owns this thread's row (0/1)
    const int l = tid & 255;            // row within phase

    float x[17];
#pragma unroll
    for (int j = 0; j < 17; ++j) x[j] = 1.0f;   // benign defaults for inactive lanes
    bool active = false;

    for (int p = 0; p < 2; ++p) {
        const int pb = base + p * PHASE;
        int rem = nrows - pb; if (rem < 0) rem = 0;
        const int rows = rem < PHASE ? rem : PHASE;
        if (rows == PHASE) {
            const float4* src = reinterpret_cast<const float4*>(xu + (size_t)pb * 17);
            float4* dst = reinterpret_cast<float4*>(s_io);
            for (int k = tid; k < PHASE * 17 / 4; k += BLOCK) dst[k] = src[k];
        } else {
            for (int k = tid; k < rows * 17; k += BLOCK) s_io[k] = xu[(size_t)pb * 17 + k];
        }
        __syncthreads();
        if (own == p && l < rows) {
            active = true;
#pragma unroll
            for (int j = 2; j < 17; ++j) x[j] = s_io[l * 17 + j];   // cols 0,1 unused
        }
        __syncthreads();
    }

    __builtin_amdgcn_s_setprio(1);      // favor compute waves over neighbor-block staging

    // ---------------- per-row physics ----------------------------------------
    const float g = 32.17f, m_ = 636.94f, Bs = 30.0f, S = 300.0f, cbar = 11.32f;
    const float xcgr = 0.35f, xcg = 0.25f;
    const float Jy = 55814.0f, Jxz = 982.0f, Jz = 63100.0f, Jx = 9496.0f;
    const float r2d = 57.29577951308232f;

    const float alt = x[2], phi = x[3], theta = x[4], psi = x[5];
    const float vt = fmaxf(x[6], 0.01f);
    const float alpha = x[7], beta = x[8];
    const float a_deg = alpha * r2d, b_deg = beta * r2d;
    const float P = x[9], Q = x[10], R = x[11];
    const float T = x[12], el = x[13], ail = x[14], rud = x[15], lef = x[16];

    const float dail = ail * (1.0f / 21.5f);
    const float drud = rud * (1.0f / 30.0f);
    const float dlef = 1.0f - lef * (1.0f / 25.0f);

    const float tfac = 1.0f - 7.03e-6f * alt;
    const float rho = 0.002377f * __expf(4.14f * __logf(tfac));
    const float qbar = 0.5f * rho * vt * vt;

    float sa, ca, sb, cb, st, ct, sphi, cphi, spsi, cpsi;
    __sincosf(alpha, &sa, &ca);
    __sincosf(beta, &sb, &cb);
    __sincosf(theta, &st, &ct);
    __sincosf(phi, &sphi, &cphi);
    __sincosf(psi, &spsi, &cpsi);
    const float tt = st / ct;

    int ia, ib, ie; float fa, fb, fe;
    idx_of(a_deg, -20.0f, 19.0f / 110.0f, 20, ia, fa);
    idx_of(b_deg, -30.0f, 18.0f / 60.0f, 19, ib, fb);
    idx_of(el,    -25.0f,  4.0f / 50.0f,  5, ie, fe);

    const float wa[2] = {1.0f - fa, fa};
    const float wb[2] = {1.0f - fb, fb};
    const float we[2] = {1.0f - fe, fe};

    // --- trilinear v3 (5ch, bf16 ch0-3 + f32 ch4) and bilinear-at-e=2 v30 ---
    float v3c[5]  = {0, 0, 0, 0, 0};
    float v30c[5] = {0, 0, 0, 0, 0};
#pragma unroll
    for (int di = 0; di < 2; ++di) {
#pragma unroll
        for (int dj = 0; dj < 2; ++dj) {
            const float wab = wa[di] * wb[dj];
            const int pb3 = ((ia + di) * 19 + (ib + dj)) * 5;
#pragma unroll
            for (int dk = 0; dk < 2; ++dk) {
                const int idx = pb3 + ie + dk;
                const uint2 qp = *reinterpret_cast<const uint2*>(&s_t3a[idx << 1]);
                const float w = wab * we[dk];
                v3c[0] += bflo(qp.x) * w; v3c[1] += bfhi(qp.x) * w;
                v3c[2] += bflo(qp.y) * w; v3c[3] += bfhi(qp.y) * w;
                v3c[4] += s_t3b[idx] * w;
            }
            const int zidx = pb3 + 2;       // el = 0 -> ie = 2, fe = 0 exactly
            const uint2 q0 = *reinterpret_cast<const uint2*>(&s_t3a[zidx << 1]);
            v30c[0] += bflo(q0.x) * wab; v30c[1] += bfhi(q0.x) * wab;
            v30c[2] += bflo(q0.y) * wab; v30c[3] += bfhi(q0.y) * wab;
            v30c[4] += s_t3b[zidx] * wab;
        }
    }

    // --- bilinear v2 (16ch), bf16-packed: 2 b128 per corner ---
    float v2c[16];
    {
        const float w00 = wa[0] * wb[0], w01 = wa[0] * wb[1];
        const float w10 = wa[1] * wb[0], w11 = wa[1] * wb[1];
        const int i00 = ia * 19 + ib;
        const uint4 a0 = *reinterpret_cast<const uint4*>(&s_tab2[i00 * 12]);
        const uint4 a1 = *reinterpret_cast<const uint4*>(&s_tab2[i00 * 12 + 4]);
        const uint4 b0 = *reinterpret_cast<const uint4*>(&s_tab2[(i00 + 1) * 12]);
        const uint4 b1 = *reinterpret_cast<const uint4*>(&s_tab2[(i00 + 1) * 12 + 4]);
        const uint4 c0 = *reinterpret_cast<const uint4*>(&s_tab2[(i00 + 19) * 12]);
        const uint4 c1 = *reinterpret_cast<const uint4*>(&s_tab2[(i00 + 19) * 12 + 4]);
        const uint4 d0 = *reinterpret_cast<const uint4*>(&s_tab2[(i00 + 20) * 12]);
        const uint4 d1 = *reinterpret_cast<const uint4*>(&s_tab2[(i00 + 20) * 12 + 4]);
        const uint_t qa[8] = {a0.x, a0.y, a0.z, a0.w, a1.x, a1.y, a1.z, a1.w};
        const uint_t qb[8] = {b0.x, b0.y, b0.z, b0.w, b1.x, b1.y, b1.z, b1.w};
        const uint_t qc[8] = {c0.x, c0.y, c0.z, c0.w, c1.x, c1.y, c1.z, c1.w};
        const uint_t qd[8] = {d0.x, d0.y, d0.z, d0.w, d1.x, d1.y, d1.z, d1.w};
#pragma unroll
        for (int d = 0; d < 8; ++d) {
            v2c[2 * d]     = bflo(qa[d]) * w00 + bflo(qb[d]) * w01
                           + bflo(qc[d]) * w10 + bflo(qd[d]) * w11;
            v2c[2 * d + 1] = bfhi(qa[d]) * w00 + bfhi(qb[d]) * w01
                           + bfhi(qc[d]) * w10 + bfhi(qd[d]) * w11;
        }
    }

    // --- linear v1 (21ch): 5 b128 + 1 b32 per row (stride-28, 16B-aligned) ---
    float v1c[21];
    {
        const float4* r0 = reinterpret_cast<const float4*>(&s_tab1[ia * 28]);
        const float4* r1 = reinterpret_cast<const float4*>(&s_tab1[(ia + 1) * 28]);
#pragma unroll
        for (int q = 0; q < 5; ++q) {
            const float4 a = r0[q], b = r1[q];
            v1c[4 * q + 0] = a.x * wa[0] + b.x * wa[1];
            v1c[4 * q + 1] = a.y * wa[0] + b.y * wa[1];
            v1c[4 * q + 2] = a.z * wa[0] + b.z * wa[1];
            v1c[4 * q + 3] = a.w * wa[0] + b.w * wa[1];
        }
        v1c[20] = s_tab1[ia * 28 + 20] * wa[0] + s_tab1[(ia + 1) * 28 + 20] * wa[1];
    }
    const float eta_el = s_tab1[560 + ie] * we[0] + s_tab1[561 + ie] * we[1];

    // --- unpack ---
    const float Cx = v3c[0], Cz = v3c[1], Cm = v3c[2], Cn = v3c[3], Cl = v3c[4];
    const float Cy = v2c[0];
    const float Cxq = v1c[0], Cyr = v1c[1], Cyp = v1c[2], Czq = v1c[3], Clr = v1c[4];
    const float Clp = v1c[5], Cmq = v1c[6], Cnr = v1c[7], Cnp = v1c[8];
    const float dCxq_lef = v1c[9], dCyr_lef = v1c[10], dCyp_lef = v1c[11];
    const float dCzq_lef = v1c[12], dClr_lef = v1c[13], dClp_lef = v1c[14];
    const float dCmq_lef = v1c[15], dCnr_lef = v1c[16], dCnp_lef = v1c[17];
    const float dCnbeta = v1c[18], dClbeta = v1c[19], dCm = v1c[20];

    const float d_Cx_lef = v2c[1] - v30c[0];
    const float d_Cz_lef = v2c[2] - v30c[1];
    const float d_Cm_lef = v2c[3] - v30c[2];
    const float d_Cy_lef = v2c[4] - v2c[0];
    const float d_Cn_lef = v2c[5] - v30c[3];
    const float d_Cl_lef = v2c[6] - v30c[4];
    const float d_Cy_r30 = v2c[7] - v2c[0];
    const float d_Cn_r30 = v2c[8] - v30c[3];
    const float d_Cl_r30 = v2c[9] - v30c[4];
    const float d_Cy_a20 = v2c[10] - v2c[0];
    const float d_Cy_a20_lef = v2c[11] - v2c[4];
    const float d_Cn_a20 = v2c[12] - v30c[3];
    const float d_Cn_a20_lef = v2c[13] - v2c[5];
    const float d_Cl_a20 = v2c[14] - v30c[4];
    const float d_Cl_a20_lef = v2c[15] - v2c[6];

    // --- kinematics ---
    const float U = vt * ca * cb, V = vt * sb, W = vt * sa * cb;
    const float o0 = U * (ct * cpsi) + V * (sphi * cpsi * st - cphi * spsi) + W * (cphi * st * cpsi + sphi * spsi);
    const float o1 = U * (ct * spsi) + V * (sphi * spsi * st + cphi * cpsi) + W * (cphi * st * spsi - sphi * cpsi);
    const float o2 = U * st - V * (sphi * ct) - W * (cphi * ct);
    const float o3 = P + tt * (Q * sphi + R * cphi);
    const float o4 = Q * cphi - R * sphi;
    const float o5 = (Q * sphi + R * cphi) / ct;

    // --- coefficients ---
    const float c2v = 1.0f / (2.0f * vt);
    const float cq = cbar * c2v, bq = Bs * c2v;
    const float dXdQ = cq * (Cxq + dCxq_lef * dlef);
    const float Cx_tot = Cx + d_Cx_lef * dlef + dXdQ * Q;
    const float dZdQ = cq * (Czq + dCzq_lef * dlef);
    const float Cz_tot = Cz + d_Cz_lef * dlef + dZdQ * Q;
    const float dMdQ = cq * (Cmq + dCmq_lef * dlef);
    const float Cm_tot = Cm * eta_el + Cz_tot * (xcgr - xcg) + d_Cm_lef * dlef + dMdQ * Q + dCm;
    const float dYdail = d_Cy_a20 + d_Cy_a20_lef * dlef;
    const float dYdR = bq * (Cyr + dCyr_lef * dlef);
    const float dYdP = bq * (Cyp + dCyp_lef * dlef);
    const float Cy_tot = Cy + d_Cy_lef * dlef + dYdail * dail + d_Cy_r30 * drud + dYdR * R + dYdP * P;
    const float dNdail = d_Cn_a20 + d_Cn_a20_lef * dlef;
    const float dNdR = bq * (Cnr + dCnr_lef * dlef);
    const float dNdP = bq * (Cnp + dCnp_lef * dlef);
    const float Cn_tot = Cn + d_Cn_lef * dlef - Cy_tot * ((xcgr - xcg) * (cbar / Bs))
                       + dNdail * dail + d_Cn_r30 * drud + dNdR * R + dNdP * P + dCnbeta * b_deg;
    const float dLdail = d_Cl_a20 + d_Cl_a20_lef * dlef;
    const float dLdR = bq * (Clr + dClr_lef * dlef);
    const float dLdP = bq * (Clp + dClp_lef * dlef);
    const float Cl_tot = Cl + d_Cl_lef * dlef + dLdail * dail + d_Cl_r30 * drud
                       + dLdR * R + dLdP * P + dClbeta * b_deg;

    // --- forces / moments ---
    const float qS = qbar * S;
    const float qS_m = qS * (1.0f / m_);
    const float Udot = R * V - Q * W - g * st + qS_m * Cx_tot + T * (1.0f / m_);
    const float Vdot = P * W - R * U + g * ct * sphi + qS_m * Cy_tot;
    const float Wdot = Q * U - P * V + g * ct * cphi + qS_m * Cz_tot;
    const float o6 = (U * Udot + V * Vdot + W * Wdot) / vt;
    const float o7 = (U * Wdot - W * Udot) / (U * U + W * W);
    const float o8 = (Vdot * vt - V * o6) / (vt * vt * cb);

    const float L_tot = Cl_tot * qS * Bs;
    const float M_tot = Cm_tot * qS * cbar;
    const float N_tot = Cn_tot * qS * Bs;
    const float denom = Jx * Jz - Jxz * Jxz;
    const float inv_denom = 1.0f / denom;   // compile-time constant
    const float o9  = (Jz * L_tot + Jxz * N_tot - (Jz * (Jz - Jy) + Jxz * Jxz) * Q * R
                      + Jxz * (Jx - Jy + Jz) * P * Q) * inv_denom;           // Heng = 0
    const float o10 = (M_tot + (Jz - Jx) * P * R - Jxz * (P * P - R * R)) * (1.0f / Jy);
    const float o11 = (Jx * N_tot + Jxz * L_tot + (Jx * (Jx - Jy) + Jxz * Jxz) * P * Q
                      - Jxz * (Jx - Jy + Jz) * Q * R) * inv_denom;

    __builtin_amdgcn_s_setprio(0);      // back to normal for IO staging

    const float o[17] = {o0, o1, o2, o3, o4, o5, o6, o7, o8, o9, o10, o11,
                         0.0f, 0.0f, 0.0f, 0.0f, 0.0f};

    // ---------------- output: 2 phases x 256 rows (LDS-staged, coalesced) -----
    for (int p = 0; p < 2; ++p) {
        const int pb = base + p * PHASE;
        int rem = nrows - pb; if (rem < 0) rem = 0;
        const int rows = rem < PHASE ? rem : PHASE;
        if (own == p && active) {
            float* orow = &s_io[l * 17];
#pragma unroll
            for (int j = 0; j < 17; ++j) orow[j] = o[j];
        }
        __syncthreads();
        if (rows == PHASE) {
            const float4* src = reinterpret_cast<const float4*>(s_io);
            float4* dst = reinterpret_cast<float4*>(out + (size_t)pb * 17);
            for (int k = tid; k < PHASE * 17 / 4; k += BLOCK) dst[k] = src[k];
        } else {
            for (int k = tid; k < rows * 17; k += BLOCK) out[(size_t)pb * 17 + k] = s_io[k];
        }
        __syncthreads();
    }
}

extern "C" void kernel_launch(void* const* d_in, const int* in_sizes, int n_in,
                              void* d_out, int out_size, void* d_ws, size_t ws_size,
                              hipStream_t stream) {
    const float* xu      = (const float*)d_in[0];
    const float* tab3    = (const float*)d_in[1];
    const float* tab2    = (const float*)d_in[2];
    const float* tab1    = (const float*)d_in[3];
    const float* tab_eta = (const float*)d_in[4];
    float* out = (float*)d_out;

    const int nrows = in_sizes[0] / 17;
    const int grid = (nrows + ROWS_PER_BLOCK - 1) / ROWS_PER_BLOCK;
    nlplant_kernel<<<grid, BLOCK, 0, stream>>>(xu, tab3, tab2, tab1, tab_eta, out, nrows);
}

// Round 22
// 54.983 us; speedup vs baseline: 1.0538x; 1.0538x over previous
//
#include <hip/hip_runtime.h>

#define BLOCK 512
#define ROWS_PER_BLOCK 512
#define PHASE 256

typedef unsigned int uint_t;

__device__ __forceinline__ unsigned short f2bf(float f) {   // RNE f32->bf16
    uint_t u = __builtin_bit_cast(uint_t, f);
    u = u + 0x7FFFu + ((u >> 16) & 1u);
    return (unsigned short)(u >> 16);
}
__device__ __forceinline__ float bflo(uint_t u) { uint_t v = u << 16;         return __builtin_bit_cast(float, v); }
__device__ __forceinline__ float bfhi(uint_t u) { uint_t v = u & 0xFFFF0000u; return __builtin_bit_cast(float, v); }

__device__ __forceinline__ void idx_of(float x, float lo, float inv_range_times_nm1,
                                       int n, int& i0, float& f) {
    float t = (x - lo) * inv_range_times_nm1;
    t = fminf(fmaxf(t, 0.0f), (float)(n - 1));
    int i = (int)t;                 // t >= 0, truncation == floor
    if (i > n - 2) i = n - 2;
    i0 = i;
    f = t - (float)i;
}

__global__ __launch_bounds__(BLOCK, 4)
void nlplant_kernel(const float* __restrict__ xu,
                    const float* __restrict__ tab3,
                    const float* __restrict__ tab2,
                    const float* __restrict__ tab1,
                    const float* __restrict__ tab_eta,
                    float* __restrict__ out, int nrows)
{
    // FINAL CHAMPION (R18, reproduced R20: 55.5-55.8us bench / ~84us rocprof).
    // R21's setprio variant was -4% (zero-sum priority between symmetric
    // co-resident blocks) -> reverted. Load-bearing structure, each violated
    // variant regressed with counter evidence:
    //  * 512-thread blocks, 2 blocks/CU (16 waves = VGPR=64 pool limit; VGPR<64
    //    spills R6; LDS-shrink does NOT raise occupancy R13)
    //  * single pass, grid 2048 (multi-pass inflates HBM traffic R11/R13/R17)
    //  * IO cadence: 2 phases x 256 rows, LDS-staged BOTH directions with
    //    float4-coalesced global transactions (direct stride-17 IO R10/R16 and
    //    single 512-row burst R19 amplified HBM traffic 2-4x)
    //  * no setprio (R21), no 2-row ILP (R15), no DMA prefetch (R8)
    //  s_t3a : tab3 ch0-3 bf16-packed                                  15200 B
    //  s_t3b : tab3 ch4 f32 flat (bank = idx%32, uniform)               7600 B
    //  s_tab2: bf16-packed, 8 dwords/corner, stride 12                 18240 B
    //  s_tab1: f32 stride-28 rows; eta tail @560                        2272 B
    //  s_io  : 256 rows x 17 in/out staging                            17408 B
    // Total 60720 B.
    __shared__ uint_t s_t3a[1900 * 2];
    __shared__ float  s_t3b[1900];
    __shared__ __align__(16) uint_t s_tab2[380 * 12];
    __shared__ __align__(16) float  s_tab1[568];
    __shared__ __align__(16) float  s_io[PHASE * 17];

    const int tid = threadIdx.x;

    // ---------------- stage tables: coalesced reads, zero div/mod -------------
    for (int idx = tid; idx < 1900; idx += BLOCK) {    // tab3 src [c][a][b][e]
        const float c0 = tab3[idx],        c1 = tab3[1900 + idx];
        const float c2 = tab3[3800 + idx], c3 = tab3[5700 + idx];
        s_t3a[2 * idx]     = (uint_t)f2bf(c0) | ((uint_t)f2bf(c1) << 16);
        s_t3a[2 * idx + 1] = (uint_t)f2bf(c2) | ((uint_t)f2bf(c3) << 16);
        s_t3b[idx] = tab3[7600 + idx];
    }
    if (tid < 380) {                                   // tab2 src [c][a][b]
#pragma unroll
        for (int d = 0; d < 8; ++d) {
            const float e0 = tab2[(2 * d) * 380 + tid];
            const float e1 = tab2[(2 * d + 1) * 380 + tid];
            s_tab2[tid * 12 + d] = (uint_t)f2bf(e0) | ((uint_t)f2bf(e1) << 16);
        }
    }
    if (tid < 420) {                                   // tab1 src [c][a]
        const int ch = tid / 20;                       // const-divide -> magic mul
        const int ia = tid - ch * 20;
        s_tab1[ia * 28 + ch] = tab1[tid];
    }
    if (tid < 5) s_tab1[560 + tid] = tab_eta[tid];
    // (first phase barrier below covers table staging)

    // ---------------- input: 2 phases x 256 rows ------------------------------
    const int base = blockIdx.x * ROWS_PER_BLOCK;
    const int own = tid >> 8;           // phase that owns this thread's row (0/1)
    const int l = tid & 255;            // row within phase

    float x[17];
#pragma unroll
    for (int j = 0; j < 17; ++j) x[j] = 1.0f;   // benign defaults for inactive lanes
    bool active = false;

    for (int p = 0; p < 2; ++p) {
        const int pb = base + p * PHASE;
        int rem = nrows - pb; if (rem < 0) rem = 0;
        const int rows = rem < PHASE ? rem : PHASE;
        if (rows == PHASE) {
            const float4* src = reinterpret_cast<const float4*>(xu + (size_t)pb * 17);
            float4* dst = reinterpret_cast<float4*>(s_io);
            for (int k = tid; k < PHASE * 17 / 4; k += BLOCK) dst[k] = src[k];
        } else {
            for (int k = tid; k < rows * 17; k += BLOCK) s_io[k] = xu[(size_t)pb * 17 + k];
        }
        __syncthreads();
        if (own == p && l < rows) {
            active = true;
#pragma unroll
            for (int j = 2; j < 17; ++j) x[j] = s_io[l * 17 + j];   // cols 0,1 unused
        }
        __syncthreads();
    }

    // ---------------- per-row physics ----------------------------------------
    const float g = 32.17f, m_ = 636.94f, Bs = 30.0f, S = 300.0f, cbar = 11.32f;
    const float xcgr = 0.35f, xcg = 0.25f;
    const float Jy = 55814.0f, Jxz = 982.0f, Jz = 63100.0f, Jx = 9496.0f;
    const float r2d = 57.29577951308232f;

    const float alt = x[2], phi = x[3], theta = x[4], psi = x[5];
    const float vt = fmaxf(x[6], 0.01f);
    const float alpha = x[7], beta = x[8];
    const float a_deg = alpha * r2d, b_deg = beta * r2d;
    const float P = x[9], Q = x[10], R = x[11];
    const float T = x[12], el = x[13], ail = x[14], rud = x[15], lef = x[16];

    const float dail = ail * (1.0f / 21.5f);
    const float drud = rud * (1.0f / 30.0f);
    const float dlef = 1.0f - lef * (1.0f / 25.0f);

    const float tfac = 1.0f - 7.03e-6f * alt;
    const float rho = 0.002377f * __expf(4.14f * __logf(tfac));
    const float qbar = 0.5f * rho * vt * vt;

    float sa, ca, sb, cb, st, ct, sphi, cphi, spsi, cpsi;
    __sincosf(alpha, &sa, &ca);
    __sincosf(beta, &sb, &cb);
    __sincosf(theta, &st, &ct);
    __sincosf(phi, &sphi, &cphi);
    __sincosf(psi, &spsi, &cpsi);
    const float tt = st / ct;

    int ia, ib, ie; float fa, fb, fe;
    idx_of(a_deg, -20.0f, 19.0f / 110.0f, 20, ia, fa);
    idx_of(b_deg, -30.0f, 18.0f / 60.0f, 19, ib, fb);
    idx_of(el,    -25.0f,  4.0f / 50.0f,  5, ie, fe);

    const float wa[2] = {1.0f - fa, fa};
    const float wb[2] = {1.0f - fb, fb};
    const float we[2] = {1.0f - fe, fe};

    // --- trilinear v3 (5ch, bf16 ch0-3 + f32 ch4) and bilinear-at-e=2 v30 ---
    float v3c[5]  = {0, 0, 0, 0, 0};
    float v30c[5] = {0, 0, 0, 0, 0};
#pragma unroll
    for (int di = 0; di < 2; ++di) {
#pragma unroll
        for (int dj = 0; dj < 2; ++dj) {
            const float wab = wa[di] * wb[dj];
            const int pb3 = ((ia + di) * 19 + (ib + dj)) * 5;
#pragma unroll
            for (int dk = 0; dk < 2; ++dk) {
                const int idx = pb3 + ie + dk;
                const uint2 qp = *reinterpret_cast<const uint2*>(&s_t3a[idx << 1]);
                const float w = wab * we[dk];
                v3c[0] += bflo(qp.x) * w; v3c[1] += bfhi(qp.x) * w;
                v3c[2] += bflo(qp.y) * w; v3c[3] += bfhi(qp.y) * w;
                v3c[4] += s_t3b[idx] * w;
            }
            const int zidx = pb3 + 2;       // el = 0 -> ie = 2, fe = 0 exactly
            const uint2 q0 = *reinterpret_cast<const uint2*>(&s_t3a[zidx << 1]);
            v30c[0] += bflo(q0.x) * wab; v30c[1] += bfhi(q0.x) * wab;
            v30c[2] += bflo(q0.y) * wab; v30c[3] += bfhi(q0.y) * wab;
            v30c[4] += s_t3b[zidx] * wab;
        }
    }

    // --- bilinear v2 (16ch), bf16-packed: 2 b128 per corner ---
    float v2c[16];
    {
        const float w00 = wa[0] * wb[0], w01 = wa[0] * wb[1];
        const float w10 = wa[1] * wb[0], w11 = wa[1] * wb[1];
        const int i00 = ia * 19 + ib;
        const uint4 a0 = *reinterpret_cast<const uint4*>(&s_tab2[i00 * 12]);
        const uint4 a1 = *reinterpret_cast<const uint4*>(&s_tab2[i00 * 12 + 4]);
        const uint4 b0 = *reinterpret_cast<const uint4*>(&s_tab2[(i00 + 1) * 12]);
        const uint4 b1 = *reinterpret_cast<const uint4*>(&s_tab2[(i00 + 1) * 12 + 4]);
        const uint4 c0 = *reinterpret_cast<const uint4*>(&s_tab2[(i00 + 19) * 12]);
        const uint4 c1 = *reinterpret_cast<const uint4*>(&s_tab2[(i00 + 19) * 12 + 4]);
        const uint4 d0 = *reinterpret_cast<const uint4*>(&s_tab2[(i00 + 20) * 12]);
        const uint4 d1 = *reinterpret_cast<const uint4*>(&s_tab2[(i00 + 20) * 12 + 4]);
        const uint_t qa[8] = {a0.x, a0.y, a0.z, a0.w, a1.x, a1.y, a1.z, a1.w};
        const uint_t qb[8] = {b0.x, b0.y, b0.z, b0.w, b1.x, b1.y, b1.z, b1.w};
        const uint_t qc[8] = {c0.x, c0.y, c0.z, c0.w, c1.x, c1.y, c1.z, c1.w};
        const uint_t qd[8] = {d0.x, d0.y, d0.z, d0.w, d1.x, d1.y, d1.z, d1.w};
#pragma unroll
        for (int d = 0; d < 8; ++d) {
            v2c[2 * d]     = bflo(qa[d]) * w00 + bflo(qb[d]) * w01
                           + bflo(qc[d]) * w10 + bflo(qd[d]) * w11;
            v2c[2 * d + 1] = bfhi(qa[d]) * w00 + bfhi(qb[d]) * w01
                           + bfhi(qc[d]) * w10 + bfhi(qd[d]) * w11;
        }
    }

    // --- linear v1 (21ch): 5 b128 + 1 b32 per row (stride-28, 16B-aligned) ---
    float v1c[21];
    {
        const float4* r0 = reinterpret_cast<const float4*>(&s_tab1[ia * 28]);
        const float4* r1 = reinterpret_cast<const float4*>(&s_tab1[(ia + 1) * 28]);
#pragma unroll
        for (int q = 0; q < 5; ++q) {
            const float4 a = r0[q], b = r1[q];
            v1c[4 * q + 0] = a.x * wa[0] + b.x * wa[1];
            v1c[4 * q + 1] = a.y * wa[0] + b.y * wa[1];
            v1c[4 * q + 2] = a.z * wa[0] + b.z * wa[1];
            v1c[4 * q + 3] = a.w * wa[0] + b.w * wa[1];
        }
        v1c[20] = s_tab1[ia * 28 + 20] * wa[0] + s_tab1[(ia + 1) * 28 + 20] * wa[1];
    }
    const float eta_el = s_tab1[560 + ie] * we[0] + s_tab1[561 + ie] * we[1];

    // --- unpack ---
    const float Cx = v3c[0], Cz = v3c[1], Cm = v3c[2], Cn = v3c[3], Cl = v3c[4];
    const float Cy = v2c[0];
    const float Cxq = v1c[0], Cyr = v1c[1], Cyp = v1c[2], Czq = v1c[3], Clr = v1c[4];
    const float Clp = v1c[5], Cmq = v1c[6], Cnr = v1c[7], Cnp = v1c[8];
    const float dCxq_lef = v1c[9], dCyr_lef = v1c[10], dCyp_lef = v1c[11];
    const float dCzq_lef = v1c[12], dClr_lef = v1c[13], dClp_lef = v1c[14];
    const float dCmq_lef = v1c[15], dCnr_lef = v1c[16], dCnp_lef = v1c[17];
    const float dCnbeta = v1c[18], dClbeta = v1c[19], dCm = v1c[20];

    const float d_Cx_lef = v2c[1] - v30c[0];
    const float d_Cz_lef = v2c[2] - v30c[1];
    const float d_Cm_lef = v2c[3] - v30c[2];
    const float d_Cy_lef = v2c[4] - v2c[0];
    const float d_Cn_lef = v2c[5] - v30c[3];
    const float d_Cl_lef = v2c[6] - v30c[4];
    const float d_Cy_r30 = v2c[7] - v2c[0];
    const float d_Cn_r30 = v2c[8] - v30c[3];
    const float d_Cl_r30 = v2c[9] - v30c[4];
    const float d_Cy_a20 = v2c[10] - v2c[0];
    const float d_Cy_a20_lef = v2c[11] - v2c[4];
    const float d_Cn_a20 = v2c[12] - v30c[3];
    const float d_Cn_a20_lef = v2c[13] - v2c[5];
    const float d_Cl_a20 = v2c[14] - v30c[4];
    const float d_Cl_a20_lef = v2c[15] - v2c[6];

    // --- kinematics ---
    const float U = vt * ca * cb, V = vt * sb, W = vt * sa * cb;
    const float o0 = U * (ct * cpsi) + V * (sphi * cpsi * st - cphi * spsi) + W * (cphi * st * cpsi + sphi * spsi);
    const float o1 = U * (ct * spsi) + V * (sphi * spsi * st + cphi * cpsi) + W * (cphi * st * spsi - sphi * cpsi);
    const float o2 = U * st - V * (sphi * ct) - W * (cphi * ct);
    const float o3 = P + tt * (Q * sphi + R * cphi);
    const float o4 = Q * cphi - R * sphi;
    const float o5 = (Q * sphi + R * cphi) / ct;

    // --- coefficients ---
    const float c2v = 1.0f / (2.0f * vt);
    const float cq = cbar * c2v, bq = Bs * c2v;
    const float dXdQ = cq * (Cxq + dCxq_lef * dlef);
    const float Cx_tot = Cx + d_Cx_lef * dlef + dXdQ * Q;
    const float dZdQ = cq * (Czq + dCzq_lef * dlef);
    const float Cz_tot = Cz + d_Cz_lef * dlef + dZdQ * Q;
    const float dMdQ = cq * (Cmq + dCmq_lef * dlef);
    const float Cm_tot = Cm * eta_el + Cz_tot * (xcgr - xcg) + d_Cm_lef * dlef + dMdQ * Q + dCm;
    const float dYdail = d_Cy_a20 + d_Cy_a20_lef * dlef;
    const float dYdR = bq * (Cyr + dCyr_lef * dlef);
    const float dYdP = bq * (Cyp + dCyp_lef * dlef);
    const float Cy_tot = Cy + d_Cy_lef * dlef + dYdail * dail + d_Cy_r30 * drud + dYdR * R + dYdP * P;
    const float dNdail = d_Cn_a20 + d_Cn_a20_lef * dlef;
    const float dNdR = bq * (Cnr + dCnr_lef * dlef);
    const float dNdP = bq * (Cnp + dCnp_lef * dlef);
    const float Cn_tot = Cn + d_Cn_lef * dlef - Cy_tot * ((xcgr - xcg) * (cbar / Bs))
                       + dNdail * dail + d_Cn_r30 * drud + dNdR * R + dNdP * P + dCnbeta * b_deg;
    const float dLdail = d_Cl_a20 + d_Cl_a20_lef * dlef;
    const float dLdR = bq * (Clr + dClr_lef * dlef);
    const float dLdP = bq * (Clp + dClp_lef * dlef);
    const float Cl_tot = Cl + d_Cl_lef * dlef + dLdail * dail + d_Cl_r30 * drud
                       + dLdR * R + dLdP * P + dClbeta * b_deg;

    // --- forces / moments ---
    const float qS = qbar * S;
    const float qS_m = qS * (1.0f / m_);
    const float Udot = R * V - Q * W - g * st + qS_m * Cx_tot + T * (1.0f / m_);
    const float Vdot = P * W - R * U + g * ct * sphi + qS_m * Cy_tot;
    const float Wdot = Q * U - P * V + g * ct * cphi + qS_m * Cz_tot;
    const float o6 = (U * Udot + V * Vdot + W * Wdot) / vt;
    const float o7 = (U * Wdot - W * Udot) / (U * U + W * W);
    const float o8 = (Vdot * vt - V * o6) / (vt * vt * cb);

    const float L_tot = Cl_tot * qS * Bs;
    const float M_tot = Cm_tot * qS * cbar;
    const float N_tot = Cn_tot * qS * Bs;
    const float denom = Jx * Jz - Jxz * Jxz;
    const float inv_denom = 1.0f / denom;   // compile-time constant
    const float o9  = (Jz * L_tot + Jxz * N_tot - (Jz * (Jz - Jy) + Jxz * Jxz) * Q * R
                      + Jxz * (Jx - Jy + Jz) * P * Q) * inv_denom;           // Heng = 0
    const float o10 = (M_tot + (Jz - Jx) * P * R - Jxz * (P * P - R * R)) * (1.0f / Jy);
    const float o11 = (Jx * N_tot + Jxz * L_tot + (Jx * (Jx - Jy) + Jxz * Jxz) * P * Q
                      - Jxz * (Jx - Jy + Jz) * Q * R) * inv_denom;

    const float o[17] = {o0, o1, o2, o3, o4, o5, o6, o7, o8, o9, o10, o11,
                         0.0f, 0.0f, 0.0f, 0.0f, 0.0f};

    // ---------------- output: 2 phases x 256 rows (LDS-staged, coalesced) -----
    for (int p = 0; p < 2; ++p) {
        const int pb = base + p * PHASE;
        int rem = nrows - pb; if (rem < 0) rem = 0;
        const int rows = rem < PHASE ? rem : PHASE;
        if (own == p && active) {
            float* orow = &s_io[l * 17];
#pragma unroll
            for (int j = 0; j < 17; ++j) orow[j] = o[j];
        }
        __syncthreads();
        if (rows == PHASE) {
            const float4* src = reinterpret_cast<const float4*>(s_io);
            float4* dst = reinterpret_cast<float4*>(out + (size_t)pb * 17);
            for (int k = tid; k < PHASE * 17 / 4; k += BLOCK) dst[k] = src[k];
        } else {
            for (int k = tid; k < rows * 17; k += BLOCK) out[(size_t)pb * 17 + k] = s_io[k];
        }
        __syncthreads();
    }
}

extern "C" void kernel_launch(void* const* d_in, const int* in_sizes, int n_in,
                              void* d_out, int out_size, void* d_ws, size_t ws_size,
                              hipStream_t stream) {
    const float* xu      = (const float*)d_in[0];
    const float* tab3    = (const float*)d_in[1];
    const float* tab2    = (const float*)d_in[2];
    const float* tab1    = (const float*)d_in[3];
    const float* tab_eta = (const float*)d_in[4];
    float* out = (float*)d_out;

    const int nrows = in_sizes[0] / 17;
    const int grid = (nrows + ROWS_PER_BLOCK - 1) / ROWS_PER_BLOCK;
    nlplant_kernel<<<grid, BLOCK, 0, stream>>>(xu, tab3, tab2, tab1, tab_eta, out, nrows);
}